// Round 1
// baseline (1814.276 us; speedup 1.0000x reference)
//
#include <hip/hip_runtime.h>
#include <cstdint>
#include <cstddef>

// Problem: GatedGCN layer. N=50000 nodes, E=640000 edges, D=128. fp32 in/out.
// ws layout (floats): NodeFeat [N*512] | aggr [N*128] | h [N*256]  => N*896 floats = 179.2 MB

__device__ __forceinline__ float4 ld4(const float* p) { return *reinterpret_cast<const float4*>(p); }

// ---------------------------------------------------------------------------
// Generic 64x64-tile fp32 GEMM: C[row0..row0+63][0..63 of this col-view] =
//   A[M,K] @ B[K,*] (+bias, optional relu, optional residual add).
// A-tile staged TRANSPOSED in LDS so the k-loop reads are ds_read_b128.
// ---------------------------------------------------------------------------
template<bool RELU, bool RES>
__device__ __forceinline__ void gemm64x64(
    const float* __restrict__ A, int lda, int M, int K, int row0,
    const float* __restrict__ B, int ldb,          // col-offset view, 64 cols used
    const float* __restrict__ bias,                // col-offset view, 64 entries
    const float* __restrict__ res, int ldr,        // col-offset view (if RES)
    float* __restrict__ C, int ldc,                // col-offset view
    float AsT[64][68], float Bs[64][64])
{
    const int t  = threadIdx.x;
    const int tx = t & 15, ty = t >> 4;            // thread computes rows ty*4+i, cols tx*4+j
    float acc[4][4] = {};

    for (int kk = 0; kk < K; kk += 64) {
        #pragma unroll
        for (int i = 0; i < 4; ++i) {
            int idx = t + i * 256;                 // 1024 float4 slots
            int r = idx >> 4, c4 = idx & 15;
            int gr = row0 + r;
            float4 v = make_float4(0.f, 0.f, 0.f, 0.f);
            if (gr < M) v = ld4(A + (size_t)gr * lda + kk + c4 * 4);
            AsT[c4 * 4 + 0][r] = v.x;              // transposed store
            AsT[c4 * 4 + 1][r] = v.y;
            AsT[c4 * 4 + 2][r] = v.z;
            AsT[c4 * 4 + 3][r] = v.w;
            int k = idx >> 4, cb = idx & 15;
            *reinterpret_cast<float4*>(&Bs[k][cb * 4]) =
                ld4(B + (size_t)(kk + k) * ldb + cb * 4);
        }
        __syncthreads();
        #pragma unroll
        for (int k = 0; k < 64; ++k) {
            float4 a4 = *reinterpret_cast<const float4*>(&AsT[k][ty * 4]);
            float4 b4 = *reinterpret_cast<const float4*>(&Bs[k][tx * 4]);
            float a[4] = {a4.x, a4.y, a4.z, a4.w};
            float b[4] = {b4.x, b4.y, b4.z, b4.w};
            #pragma unroll
            for (int i = 0; i < 4; ++i)
                #pragma unroll
                for (int j = 0; j < 4; ++j)
                    acc[i][j] = fmaf(a[i], b[j], acc[i][j]);
        }
        __syncthreads();
    }

    #pragma unroll
    for (int i = 0; i < 4; ++i) {
        int gr = row0 + ty * 4 + i;
        if (gr >= M) continue;
        #pragma unroll
        for (int j = 0; j < 4; ++j) {
            int c = tx * 4 + j;
            float v = acc[i][j] + bias[c];
            if (RELU) v = fmaxf(v, 0.f);
            if (RES)  v += res[(size_t)gr * ldr + c];
            C[(size_t)gr * ldc + c] = v;
        }
    }
}

// NodeFeat[N][512] = x @ [WA|WB|WD|WE] + [bA|bB|bD|bE]
__global__ __launch_bounds__(256) void node_gemm4_kernel(
    const float* __restrict__ x,
    const float* __restrict__ WA, const float* __restrict__ bA,
    const float* __restrict__ WB, const float* __restrict__ bB,
    const float* __restrict__ WD, const float* __restrict__ bD,
    const float* __restrict__ WE, const float* __restrict__ bE,
    float* __restrict__ NodeFeat, int N)
{
    __shared__ float AsT[64][68];
    __shared__ float Bs[64][64];
    int y = blockIdx.y, sec = y >> 1, half = (y & 1) * 64;
    const float* W = sec == 0 ? WA : sec == 1 ? WB : sec == 2 ? WD : WE;
    const float* b = sec == 0 ? bA : sec == 1 ? bB : sec == 2 ? bD : bE;
    gemm64x64<false, false>(x, 128, N, 128, blockIdx.x * 64, W + half, 128, b + half,
                            nullptr, 0, NodeFeat + (size_t)y * 64, 512, AsT, Bs);
}

__global__ __launch_bounds__(256) void ffn1_kernel(
    const float* __restrict__ xfp, const float* __restrict__ W1,
    const float* __restrict__ b1, float* __restrict__ h, int N)
{
    __shared__ float AsT[64][68];
    __shared__ float Bs[64][64];
    int cb = blockIdx.y * 64;
    gemm64x64<true, false>(xfp, 128, N, 128, blockIdx.x * 64, W1 + cb, 256, b1 + cb,
                           nullptr, 0, h + cb, 256, AsT, Bs);
}

__global__ __launch_bounds__(256) void ffn2_kernel(
    const float* __restrict__ h, const float* __restrict__ W2,
    const float* __restrict__ b2, const float* __restrict__ xfp,
    float* __restrict__ xout, int N)
{
    __shared__ float AsT[64][68];
    __shared__ float Bs[64][64];
    int cb = blockIdx.y * 64;
    gemm64x64<false, true>(h, 256, N, 256, blockIdx.x * 64, W2 + cb, 128, b2 + cb,
                           xfp + cb, 128, xout + cb, 128, AsT, Bs);
}

// ---------------------------------------------------------------------------
// Edge kernel: per 64-edge tile, Ce = edge_attr_tile @ WC (GEMM in LDS), then
// e_ij = Dx[row]+Ex[col]+Ce+bC ; e_final = edge_attr + relu(e_ij) ;
// atomicAdd(aggr[row], edge_w * sigmoid(e_ij) * Bx[col]).
// ---------------------------------------------------------------------------
__global__ __launch_bounds__(256) void edge_kernel(
    const float* __restrict__ edge_attr, const float* __restrict__ edge_w,
    const int* __restrict__ rowI, const int* __restrict__ colI,
    const float* __restrict__ WC, const float* __restrict__ bC,
    const float* __restrict__ NodeFeat,      // [N][512] = Ax|Bx|Dx|Ex
    float* __restrict__ e_final, float* __restrict__ aggr, int E)
{
    __shared__ float EaT[128][68];           // edge_attr tile, transposed [k][edge]
    __shared__ float Bs[64 * 128];           // WC k-chunk [64][128]; reused as Ce[64][128]
    __shared__ int   rS[64], cS[64];
    __shared__ float wS[64];

    const int t  = threadIdx.x;
    const int tx = t & 15, ty = t >> 4;      // GEMM: rows ty*4+i, cols tx*8+j
    const int e0 = blockIdx.x * 64;

    if (t < 64) {
        int e = e0 + t;
        rS[t] = (e < E) ? rowI[e] : 0;
        cS[t] = (e < E) ? colI[e] : 0;
        wS[t] = (e < E) ? edge_w[e] : 0.f;
    }
    #pragma unroll
    for (int i = 0; i < 8; ++i) {            // stage edge_attr tile (full K=128), transposed
        int idx = t + i * 256;               // 2048 float4 slots: (r, c4)
        int r = idx >> 5, c4 = idx & 31;
        int e = e0 + r;
        float4 v = make_float4(0.f, 0.f, 0.f, 0.f);
        if (e < E) v = ld4(edge_attr + (size_t)e * 128 + c4 * 4);
        EaT[c4 * 4 + 0][r] = v.x;
        EaT[c4 * 4 + 1][r] = v.y;
        EaT[c4 * 4 + 2][r] = v.z;
        EaT[c4 * 4 + 3][r] = v.w;
    }

    float acc[4][8] = {};
    for (int kk = 0; kk < 128; kk += 64) {
        #pragma unroll
        for (int i = 0; i < 8; ++i) {        // stage WC chunk [64][128]
            int idx = t + i * 256;
            int k = idx >> 5, c4 = idx & 31;
            *reinterpret_cast<float4*>(&Bs[k * 128 + c4 * 4]) =
                ld4(WC + (size_t)(kk + k) * 128 + c4 * 4);
        }
        __syncthreads();
        #pragma unroll
        for (int k = 0; k < 64; ++k) {
            float4 a4 = *reinterpret_cast<const float4*>(&EaT[kk + k][ty * 4]);
            float4 b0 = *reinterpret_cast<const float4*>(&Bs[k * 128 + tx * 8]);
            float4 b1 = *reinterpret_cast<const float4*>(&Bs[k * 128 + tx * 8 + 4]);
            float a[4] = {a4.x, a4.y, a4.z, a4.w};
            float b[8] = {b0.x, b0.y, b0.z, b0.w, b1.x, b1.y, b1.z, b1.w};
            #pragma unroll
            for (int i = 0; i < 4; ++i)
                #pragma unroll
                for (int j = 0; j < 8; ++j)
                    acc[i][j] = fmaf(a[i], b[j], acc[i][j]);
        }
        __syncthreads();
    }

    // dump Ce into Bs region (now free), layout [edge][feat]
    #pragma unroll
    for (int i = 0; i < 4; ++i) {
        float4 v0 = make_float4(acc[i][0], acc[i][1], acc[i][2], acc[i][3]);
        float4 v1 = make_float4(acc[i][4], acc[i][5], acc[i][6], acc[i][7]);
        *reinterpret_cast<float4*>(&Bs[(ty * 4 + i) * 128 + tx * 8])     = v0;
        *reinterpret_cast<float4*>(&Bs[(ty * 4 + i) * 128 + tx * 8 + 4]) = v1;
    }
    __syncthreads();

    // epilogue: 2 edges x 128 feats per pass
    const int f   = t & 127;
    const int sub = t >> 7;
    const float bCv = bC[f];
    for (int eo = sub; eo < 64; eo += 2) {
        int e = e0 + eo;
        if (e >= E) break;
        int r = rS[eo], c = cS[eo];
        float eij = Bs[eo * 128 + f] + bCv
                  + NodeFeat[(size_t)r * 512 + 256 + f]     // Dx[row]
                  + NodeFeat[(size_t)c * 512 + 384 + f];    // Ex[col]
        float sg  = 1.f / (1.f + __expf(-eij));
        float msg = wS[eo] * sg * NodeFeat[(size_t)c * 512 + 128 + f];  // Bx[col]
        e_final[(size_t)e * 128 + f] = EaT[f][eo] + fmaxf(eij, 0.f);
        atomicAdd(&aggr[(size_t)r * 128 + f], msg);
    }
}

// xfp = x + relu(Ax + aggr)   (written straight into d_out's x region)
__global__ __launch_bounds__(256) void node_combine(
    const float* __restrict__ x, const float* __restrict__ NodeFeat,
    const float* __restrict__ aggr, float* __restrict__ xfp, int N)
{
    int i4 = blockIdx.x * blockDim.x + threadIdx.x;   // over N*32 float4s
    if (i4 >= N * 32) return;
    int row = i4 >> 5, c4 = i4 & 31;
    float4 xa = ld4(x + (size_t)i4 * 4);
    float4 ax = ld4(NodeFeat + (size_t)row * 512 + c4 * 4);
    float4 ag = ld4(aggr + (size_t)i4 * 4);
    float4 o;
    o.x = xa.x + fmaxf(ax.x + ag.x, 0.f);
    o.y = xa.y + fmaxf(ax.y + ag.y, 0.f);
    o.z = xa.z + fmaxf(ax.z + ag.z, 0.f);
    o.w = xa.w + fmaxf(ax.w + ag.w, 0.f);
    *reinterpret_cast<float4*>(xfp + (size_t)i4 * 4) = o;
}

extern "C" void kernel_launch(void* const* d_in, const int* in_sizes, int n_in,
                              void* d_out, int out_size, void* d_ws, size_t ws_size,
                              hipStream_t stream)
{
    const float* x         = (const float*)d_in[0];
    const float* edge_attr = (const float*)d_in[1];
    const float* edge_w    = (const float*)d_in[2];
    const float* WA = (const float*)d_in[3];  const float* bA = (const float*)d_in[4];
    const float* WB = (const float*)d_in[5];  const float* bB = (const float*)d_in[6];
    const float* WC = (const float*)d_in[7];  const float* bC = (const float*)d_in[8];
    const float* WD = (const float*)d_in[9];  const float* bD = (const float*)d_in[10];
    const float* WE = (const float*)d_in[11]; const float* bE = (const float*)d_in[12];
    const float* W1 = (const float*)d_in[13]; const float* b1 = (const float*)d_in[14];
    const float* W2 = (const float*)d_in[15]; const float* b2 = (const float*)d_in[16];
    const int*   eidx = (const int*)d_in[17];

    const int N = in_sizes[0] / 128;
    const int E = in_sizes[2];
    const int* rowI = eidx;
    const int* colI = eidx + E;

    float* ws       = (float*)d_ws;
    float* NodeFeat = ws;                         // N*512
    float* aggr     = ws + (size_t)N * 512;       // N*128
    float* h        = ws + (size_t)N * 640;       // N*256
    float* xfp      = (float*)d_out;              // N*128  (x_final region)
    float* e_final  = (float*)d_out + (size_t)N * 128;

    const int rowTiles = (N + 63) / 64;

    hipMemsetAsync(aggr, 0, (size_t)N * 128 * sizeof(float), stream);
    node_gemm4_kernel<<<dim3(rowTiles, 8), 256, 0, stream>>>(
        x, WA, bA, WB, bB, WD, bD, WE, bE, NodeFeat, N);
    edge_kernel<<<dim3((E + 63) / 64), 256, 0, stream>>>(
        edge_attr, edge_w, rowI, colI, WC, bC, NodeFeat, e_final, aggr, E);
    node_combine<<<dim3((N * 32 + 255) / 256), 256, 0, stream>>>(
        x, NodeFeat, aggr, xfp, N);
    ffn1_kernel<<<dim3(rowTiles, 4), 256, 0, stream>>>(xfp, W1, b1, h, N);
    ffn2_kernel<<<dim3(rowTiles, 2), 256, 0, stream>>>(h, W2, b2, xfp, xfp, N);
}